// Round 12
// baseline (1311.054 us; speedup 1.0000x reference)
//
#include <hip/hip_runtime.h>

#define P_N 2048
#define Q_N 512
#define A_N 48
#define BA_N 96          // 2 * 48 (b, anchor) pairs
#define CAP 12           // candidate slots per thread
#define FCHUNK 128       // scan chunk between flushes
#define QTR (P_N / 4)    // points per wave

// plain numpy-f32 3-term dot: ((x*x' + y*y') + z*z'), each op separately rounded
__device__ __forceinline__ float dot3_rn(float ax, float ay, float az,
                                         float bx, float by, float bz) {
    return __fadd_rn(__fadd_rn(__fmul_rn(ax, bx), __fmul_rn(ay, by)),
                     __fmul_rn(az, bz));
}

// XLA fused mul+reduce FMA chain: fma(z,z', fma(y,y', rn(x*x')))
__device__ __forceinline__ float dot3_fma(float ax, float ay, float az,
                                          float bx, float by, float bz) {
    return __fmaf_rn(az, bz, __fmaf_rn(ay, by, __fmul_rn(ax, bx)));
}

// sorted insert (ascending) into 16-entry register list; stable for equal keys
__device__ __forceinline__ void insert16(float d, int idx, float (&td)[16], int (&ti)[16]) {
    if (d >= td[15]) return;
    #pragma unroll
    for (int j = 15; j >= 1; --j) {
        float oldd = td[j]; int oldi = ti[j];
        bool up   = (d < td[j - 1]);
        bool here = (d < oldd);
        td[j] = up ? td[j - 1] : (here ? d : oldd);
        ti[j] = up ? ti[j - 1] : (here ? idx : oldi);
    }
    if (d < td[0]) { ti[0] = idx; td[0] = d; }
}

// ---- K1: precompute per-(b,a) point slabs: (dist, dirx, diry, dirz) ----
// profile (verified): d2 plain, dist = sqrt_rn(d2), dir = vec * rn(1/dist)
__global__ __launch_bounds__(256, 4) void feat_kernel(
        const float* __restrict__ pcd, const float* __restrict__ anc,
        float4* __restrict__ slabs) {
    const int t  = blockIdx.x * 256 + threadIdx.x;   // 0 .. 196607
    const int ba = t >> 11;                          // b*48 + a
    const int p  = t & (P_N - 1);
    const int b  = ba / A_N;
    const float ax = anc[ba * 3 + 0];
    const float ay = anc[ba * 3 + 1];
    const float az = anc[ba * 3 + 2];
    const float* pp = pcd + ((size_t)b * P_N + p) * 3;
    float vx = __fsub_rn(pp[0], ax);
    float vy = __fsub_rn(pp[1], ay);
    float vz = __fsub_rn(pp[2], az);
    float d2 = dot3_rn(vx, vy, vz, vx, vy, vz);
    float dist = __fsqrt_rn(d2);
    float r = __fdiv_rn(1.0f, dist);
    slabs[t] = make_float4(dist, __fmul_rn(vx, r), __fmul_rn(vy, r), __fmul_rn(vz, r));
}

// ---- K2: cone-cast scan + top-16 + feature emit ----
__global__ __launch_bounds__(256, 3) void scan_kernel(
        const float* __restrict__ pcd, const float* __restrict__ qry,
        const float* __restrict__ anc, const float4* __restrict__ slabs,
        float* __restrict__ out) {
    // cand[k][tid] (scan phase)  UNION  merge bufs mb(buf,k,lane) (merge phase)
    __shared__ uint2 smem[CAP * 256];                // 24576 B

    const int tid  = threadIdx.x;
    const int lane = tid & 63;
    const int w    = __builtin_amdgcn_readfirstlane(tid >> 6);  // wave id 0..3

    const int bid = blockIdx.x;          // (b*48 + a)*8 + qc
    const int qc  = bid & 7;
    const int ba  = bid >> 3;            // 0..95
    const int a   = ba % A_N;
    const int b   = ba / A_N;

    const float ax = anc[ba * 3 + 0];
    const float ay = anc[ba * 3 + 1];
    const float az = anc[ba * 3 + 2];

    // per-lane query setup (identical math to passing kernel)
    const int q = (qc << 6) + lane;
    const float qx = qry[((size_t)b * Q_N + q) * 3 + 0];
    const float qy = qry[((size_t)b * Q_N + q) * 3 + 1];
    const float qz = qry[((size_t)b * Q_N + q) * 3 + 2];
    const float vqx = __fsub_rn(qx, ax);
    const float vqy = __fsub_rn(qy, ay);
    const float vqz = __fsub_rn(qz, az);
    const float qd2 = dot3_rn(vqx, vqy, vqz, vqx, vqy, vqz);
    const float qdist = __fsqrt_rn(qd2);
    const float qr = __fdiv_rn(1.0f, qdist);
    const float dqx = __fmul_rn(vqx, qr);
    const float dqy = __fmul_rn(vqy, qr);
    const float dqz = __fmul_rn(vqz, qr);

    const float COS_TH = 0.9659258262890683f;

    float td[16]; int ti[16];
    #pragma unroll
    for (int j = 0; j < 16; ++j) { td[j] = __builtin_inff(); ti[j] = 0; }

    // ---- scan this wave's point-quarter via wave-uniform slab loads ----
    const float4* slab = slabs + (size_t)ba * P_N;
    int cnt = 0;
    const int p0w = w * QTR;
    for (int c0 = p0w; c0 < p0w + QTR; c0 += FCHUNK) {
        #pragma unroll 4
        for (int p = c0; p < c0 + FCHUNK; ++p) {
            float4 pt = slab[p];                      // uniform -> scalar load
            float cosv = dot3_fma(dqx, dqy, dqz, pt.y, pt.z, pt.w);
            if (!(cosv <= COS_TH)) {                  // candidate iff !(cos <= TH)
                if (cnt == CAP) {                     // in-order overflow flush
                    for (int k = 0; k < CAP; ++k) {
                        uint2 e = smem[k * 256 + tid];
                        insert16(__uint_as_float(e.x), (int)e.y, td, ti);
                    }
                    cnt = 0;
                }
                smem[cnt * 256 + tid] = make_uint2(__float_as_uint(pt.x), (unsigned)p);
                ++cnt;
            }
        }
        for (int k = 0; k < cnt; ++k) {
            uint2 e = smem[k * 256 + tid];
            insert16(__uint_as_float(e.x), (int)e.y, td, ti);
        }
        cnt = 0;
    }

    // ---- tree merge: (w0 <- w1) || (w2 <- w3), then w0 <- w2' ----
    __syncthreads();                                  // cand lists dead; reuse smem
    if (w == 1 || w == 3) {
        uint2* mb = smem + ((w >> 1) * 16) * 64;      // w1 -> buf0, w3 -> buf1
        #pragma unroll
        for (int k = 0; k < 16; ++k)
            mb[k * 64 + lane] = make_uint2(__float_as_uint(td[k]), (unsigned)ti[k]);
    }
    __syncthreads();
    if (w == 0 || w == 2) {
        const uint2* mb = smem + ((w >> 1) * 16) * 64;
        #pragma unroll
        for (int k = 0; k < 16; ++k) {
            uint2 e = mb[k * 64 + lane];
            insert16(__uint_as_float(e.x), (int)e.y, td, ti);
        }
    }
    __syncthreads();
    if (w == 2) {
        uint2* mb = smem + 16 * 64;                   // republish merged w2+w3
        #pragma unroll
        for (int k = 0; k < 16; ++k)
            mb[k * 64 + lane] = make_uint2(__float_as_uint(td[k]), (unsigned)ti[k]);
    }
    __syncthreads();

    if (w == 0) {
        const uint2* mb = smem + 16 * 64;
        #pragma unroll
        for (int k = 0; k < 16; ++k) {
            uint2 e = mb[k * 64 + lane];
            insert16(__uint_as_float(e.x), (int)e.y, td, ti);
        }

        // ---- emit features: out[b][q][a][0..16][0..3] as float32 ----
        const float* pbase = pcd + (size_t)b * P_N * 3;
        float4* o = (float4*)(out + (((size_t)(b * Q_N + q) * A_N + a) * 17) * 4);
        o[0] = make_float4(vqx, vqy, vqz, qdist);

        #pragma unroll
        for (int j = 0; j < 16; ++j) {
            float4 wv;
            if (td[j] == __builtin_inff()) {
                wv = make_float4(0.0f, 0.0f, 0.0f, 0.0f);   // padded -> exact zeros
            } else {
                const float* hp = pbase + (size_t)ti[j] * 3;
                float hx = __fsub_rn(hp[0], qx);
                float hy = __fsub_rn(hp[1], qy);
                float hz = __fsub_rn(hp[2], qz);
                float sq = dot3_rn(hx, hy, hz, hx, hy, hz);
                float md = (sq == 0.0f) ? 0.0f : __fsqrt_rn(sq);
                wv = make_float4(hx, hy, hz, md);
            }
            o[1 + j] = wv;
        }
    }
}

// ---- fallback: round-11 fused kernel (used only if d_ws is too small) ----
__global__ __launch_bounds__(256, 3) void aronet_fallback(
        const float* __restrict__ pcd, const float* __restrict__ qry,
        const float* __restrict__ anc, float* __restrict__ out) {
    __shared__ float4 spt[P_N];
    __shared__ float  scratch_f[4896];
    unsigned short* cand = (unsigned short*)scratch_f;
    float*          mdist = scratch_f;
    unsigned short* midx  = (unsigned short*)(scratch_f + 3264);

    const int tid  = threadIdx.x;
    const int lane = tid & 63;
    const int w    = tid >> 6;
    const int bid = blockIdx.x;
    const int qc  = bid & 7;
    const int ba  = bid >> 3;
    const int a   = ba % A_N;
    const int b   = ba / A_N;

    const float ax = anc[(b * A_N + a) * 3 + 0];
    const float ay = anc[(b * A_N + a) * 3 + 1];
    const float az = anc[(b * A_N + a) * 3 + 2];

    const float* pbase = pcd + (size_t)b * P_N * 3;
    const int pq0 = w * QTR;
    for (int i = lane; i < QTR; i += 64) {
        const int p = pq0 + i;
        float vx = __fsub_rn(pbase[p * 3 + 0], ax);
        float vy = __fsub_rn(pbase[p * 3 + 1], ay);
        float vz = __fsub_rn(pbase[p * 3 + 2], az);
        float d2 = dot3_rn(vx, vy, vz, vx, vy, vz);
        float dist = __fsqrt_rn(d2);
        float r = __fdiv_rn(1.0f, dist);
        spt[p] = make_float4(dist, __fmul_rn(vx, r), __fmul_rn(vy, r), __fmul_rn(vz, r));
    }

    const int q = (qc << 6) + lane;
    const float qx = qry[((size_t)b * Q_N + q) * 3 + 0];
    const float qy = qry[((size_t)b * Q_N + q) * 3 + 1];
    const float qz = qry[((size_t)b * Q_N + q) * 3 + 2];
    const float vqx = __fsub_rn(qx, ax);
    const float vqy = __fsub_rn(qy, ay);
    const float vqz = __fsub_rn(qz, az);
    const float qd2 = dot3_rn(vqx, vqy, vqz, vqx, vqy, vqz);
    const float qdist = __fsqrt_rn(qd2);
    const float qr = __fdiv_rn(1.0f, qdist);
    const float dqx = __fmul_rn(vqx, qr);
    const float dqy = __fmul_rn(vqy, qr);
    const float dqz = __fmul_rn(vqz, qr);

    const float COS_TH = 0.9659258262890683f;
    float td[16]; int ti[16];
    #pragma unroll
    for (int j = 0; j < 16; ++j) { td[j] = __builtin_inff(); ti[j] = 0; }

    const int lbase = tid * 33;
    int cnt = 0;
    for (int c0 = pq0; c0 < pq0 + QTR; c0 += 256) {
        #pragma unroll 4
        for (int p = c0; p < c0 + 256; ++p) {
            float4 pt = spt[p];
            float cosv = dot3_fma(dqx, dqy, dqz, pt.y, pt.z, pt.w);
            if (!(cosv <= COS_TH)) {
                if (cnt < 32) { cand[lbase + cnt] = (unsigned short)p; cnt++; }
                else insert16(pt.x, p, td, ti);
            }
        }
        for (int k = 0; k < cnt; ++k) { int i = cand[lbase + k]; insert16(spt[i].x, i, td, ti); }
        cnt = 0;
    }

    __syncthreads();
    if (w > 0) {
        const int mb = ((w - 1) * 64 + lane) * 17;
        #pragma unroll
        for (int k = 0; k < 16; ++k) { mdist[mb + k] = td[k]; midx[mb + k] = (unsigned short)ti[k]; }
    }
    __syncthreads();
    if (w == 0) {
        for (int w2 = 0; w2 < 3; ++w2) {
            const int mb = (w2 * 64 + lane) * 17;
            #pragma unroll
            for (int k = 0; k < 16; ++k) {
                float d = mdist[mb + k];
                if (d < __builtin_inff()) insert16(d, (int)midx[mb + k], td, ti);
            }
        }
        float4* o = (float4*)(out + (((size_t)(b * Q_N + q) * A_N + a) * 17) * 4);
        o[0] = make_float4(vqx, vqy, vqz, qdist);
        #pragma unroll
        for (int j = 0; j < 16; ++j) {
            float4 wv;
            if (td[j] == __builtin_inff()) {
                wv = make_float4(0.0f, 0.0f, 0.0f, 0.0f);
            } else {
                const float* hp = pbase + (size_t)ti[j] * 3;
                float hx = __fsub_rn(hp[0], qx);
                float hy = __fsub_rn(hp[1], qy);
                float hz = __fsub_rn(hp[2], qz);
                float sq = dot3_rn(hx, hy, hz, hx, hy, hz);
                float md = (sq == 0.0f) ? 0.0f : __fsqrt_rn(sq);
                wv = make_float4(hx, hy, hz, md);
            }
            o[1 + j] = wv;
        }
    }
}

extern "C" void kernel_launch(void* const* d_in, const int* in_sizes, int n_in,
                              void* d_out, int out_size, void* d_ws, size_t ws_size,
                              hipStream_t stream) {
    const float* pcd = (const float*)d_in[0];
    const float* qry = (const float*)d_in[1];
    const float* anc = (const float*)d_in[2];
    float* out = (float*)d_out;

    const size_t need = (size_t)BA_N * P_N * sizeof(float4);   // 3.15 MB
    if (ws_size >= need) {
        float4* slabs = (float4*)d_ws;
        hipLaunchKernelGGL(feat_kernel, dim3(BA_N * P_N / 256), dim3(256), 0, stream,
                           pcd, anc, slabs);
        hipLaunchKernelGGL(scan_kernel, dim3(2 * A_N * 8), dim3(256), 0, stream,
                           pcd, qry, anc, slabs, out);
    } else {
        hipLaunchKernelGGL(aronet_fallback, dim3(2 * A_N * 8), dim3(256), 0, stream,
                           pcd, qry, anc, out);
    }
}

// Round 13
// 480.665 us; speedup vs baseline: 2.7276x; 2.7276x over previous
//
#include <hip/hip_runtime.h>

#define P_N 2048
#define Q_N 512
#define A_N 48
#define NW 8             // waves per block
#define WPTS 256         // points per wave (contiguous slice)
#define CAP 17           // u16 candidate slots per thread
#define FCHUNK 128       // points scanned between flushes

// plain numpy-f32 3-term dot: ((x*x' + y*y') + z*z'), each op separately rounded
__device__ __forceinline__ float dot3_rn(float ax, float ay, float az,
                                         float bx, float by, float bz) {
    return __fadd_rn(__fadd_rn(__fmul_rn(ax, bx), __fmul_rn(ay, by)),
                     __fmul_rn(az, bz));
}

// XLA fused mul+reduce FMA chain: fma(z,z', fma(y,y', rn(x*x')))
__device__ __forceinline__ float dot3_fma(float ax, float ay, float az,
                                          float bx, float by, float bz) {
    return __fmaf_rn(az, bz, __fmaf_rn(ay, by, __fmul_rn(ax, bx)));
}

// sorted insert (ascending) into 16-entry register list; stable for equal keys
__device__ __forceinline__ void insert16(float d, int idx, float (&td)[16], int (&ti)[16]) {
    if (d >= td[15]) return;
    #pragma unroll
    for (int j = 15; j >= 1; --j) {
        float oldd = td[j]; int oldi = ti[j];
        bool up   = (d < td[j - 1]);
        bool here = (d < oldd);
        td[j] = up ? td[j - 1] : (here ? d : oldd);
        ti[j] = up ? ti[j - 1] : (here ? idx : oldi);
    }
    if (d < td[0]) { ti[0] = idx; td[0] = d; }
}

__global__ __launch_bounds__(512, 6) void aronet_kernel(
        const float* __restrict__ pcd, const float* __restrict__ qry,
        const float* __restrict__ anc, float* __restrict__ out) {
    __shared__ float4 spt[NW * WPTS];            // 32 KiB; dead after scan -> merge bufs
    __shared__ unsigned short cand[512 * CAP];   // 17408 B candidate index lists

    uint2* mbuf = (uint2*)spt;                   // merge view: buf j = mbuf[j*1024 ..)

    const int tid  = threadIdx.x;
    const int lane = tid & 63;
    const int w    = tid >> 6;                   // wave id 0..7

    const int bid = blockIdx.x;                  // (b*48 + a)*8 + qc
    const int qc  = bid & 7;
    const int ba  = bid >> 3;                    // 0..95
    const int a   = ba % A_N;
    const int b   = ba / A_N;

    const float ax = anc[ba * 3 + 0];
    const float ay = anc[ba * 3 + 1];
    const float az = anc[ba * 3 + 2];

    // ---- each wave stages ITS OWN 256-point slice (no cross-wave dependency) ----
    // verified profile: d2 plain, dist = sqrt_rn(d2), dir = vec * rn(1/dist)
    const float* pbase = pcd + (size_t)b * P_N * 3;
    const int pq0 = w * WPTS;
    for (int i = lane; i < WPTS; i += 64) {
        const int p = pq0 + i;
        float vx = __fsub_rn(pbase[p * 3 + 0], ax);
        float vy = __fsub_rn(pbase[p * 3 + 1], ay);
        float vz = __fsub_rn(pbase[p * 3 + 2], az);
        float d2 = dot3_rn(vx, vy, vz, vx, vy, vz);
        float dist = __fsqrt_rn(d2);
        float r = __fdiv_rn(1.0f, dist);
        spt[p] = make_float4(dist, __fmul_rn(vx, r), __fmul_rn(vy, r), __fmul_rn(vz, r));
    }

    // ---- per-lane query setup (identical math to passing kernel) ----
    const int q = (qc << 6) + lane;
    const float qx = qry[((size_t)b * Q_N + q) * 3 + 0];
    const float qy = qry[((size_t)b * Q_N + q) * 3 + 1];
    const float qz = qry[((size_t)b * Q_N + q) * 3 + 2];
    const float vqx = __fsub_rn(qx, ax);
    const float vqy = __fsub_rn(qy, ay);
    const float vqz = __fsub_rn(qz, az);
    const float qd2 = dot3_rn(vqx, vqy, vqz, vqx, vqy, vqz);
    const float qdist = __fsqrt_rn(qd2);
    const float qr = __fdiv_rn(1.0f, qdist);
    const float dqx = __fmul_rn(vqx, qr);
    const float dqy = __fmul_rn(vqy, qr);
    const float dqz = __fmul_rn(vqz, qr);

    const float COS_TH = 0.9659258262890683f;

    float td[16]; int ti[16];
    #pragma unroll
    for (int j = 0; j < 16; ++j) { td[j] = __builtin_inff(); ti[j] = 0; }

    // ---- scan own slice: batched broadcast reads, compact, flush per chunk ----
    const int lbase = tid * CAP;
    int cnt = 0;
    for (int c0 = 0; c0 < WPTS; c0 += FCHUNK) {
        for (int i0 = c0; i0 < c0 + FCHUNK; i0 += 4) {
            float4 p0 = spt[pq0 + i0 + 0];       // 4 outstanding ds_read_b128
            float4 p1 = spt[pq0 + i0 + 1];
            float4 p2 = spt[pq0 + i0 + 2];
            float4 p3 = spt[pq0 + i0 + 3];
            #pragma unroll
            for (int u = 0; u < 4; ++u) {
                float4 pt = (u == 0) ? p0 : (u == 1) ? p1 : (u == 2) ? p2 : p3;
                float cosv = dot3_fma(dqx, dqy, dqz, pt.y, pt.z, pt.w);
                if (!(cosv <= COS_TH)) {         // candidate iff !(cos <= TH)
                    if (cnt == CAP) {            // rare in-order overflow flush
                        for (int k = 0; k < CAP; ++k) {
                            int i = cand[lbase + k];
                            insert16(spt[pq0 + i].x, pq0 + i, td, ti);
                        }
                        cnt = 0;
                    }
                    cand[lbase + cnt] = (unsigned short)(i0 + u);
                    ++cnt;
                }
            }
        }
        for (int k = 0; k < cnt; ++k) {          // chunk-end flush (ascending order)
            int i = cand[lbase + k];
            insert16(spt[pq0 + i].x, pq0 + i, td, ti);
        }
        cnt = 0;
    }

    // ---- 3-level tree merge over 8 waves (ascending wave order = ascending idx) ----
    __syncthreads();                             // all scans/flushes done; spt dead
    if (w & 1) {                                 // w1,3,5,7 -> bufs 0..3
        uint2* mb = mbuf + (w >> 1) * 1024;
        #pragma unroll
        for (int k = 0; k < 16; ++k)
            mb[k * 64 + lane] = make_uint2(__float_as_uint(td[k]), (unsigned)ti[k]);
    }
    __syncthreads();
    if (!(w & 1)) {                              // w0<-w1, w2<-w3, w4<-w5, w6<-w7
        const uint2* mb = mbuf + (w >> 1) * 1024;
        #pragma unroll
        for (int k = 0; k < 16; ++k) {
            uint2 e = mb[k * 64 + lane];
            float d = __uint_as_float(e.x);
            if (d < __builtin_inff()) insert16(d, (int)e.y, td, ti);
        }
    }
    __syncthreads();
    if (w == 2 || w == 6) {                      // republish: w2->buf0, w6->buf1
        uint2* mb = mbuf + (w >> 2) * 1024;
        #pragma unroll
        for (int k = 0; k < 16; ++k)
            mb[k * 64 + lane] = make_uint2(__float_as_uint(td[k]), (unsigned)ti[k]);
    }
    __syncthreads();
    if (w == 0 || w == 4) {                      // w0<-w2', w4<-w6'
        const uint2* mb = mbuf + (w >> 2) * 1024;
        #pragma unroll
        for (int k = 0; k < 16; ++k) {
            uint2 e = mb[k * 64 + lane];
            float d = __uint_as_float(e.x);
            if (d < __builtin_inff()) insert16(d, (int)e.y, td, ti);
        }
    }
    __syncthreads();
    if (w == 4) {                                // republish w4'' -> buf0
        uint2* mb = mbuf;
        #pragma unroll
        for (int k = 0; k < 16; ++k)
            mb[k * 64 + lane] = make_uint2(__float_as_uint(td[k]), (unsigned)ti[k]);
    }
    __syncthreads();

    if (w == 0) {
        const uint2* mb = mbuf;                  // final: w0 <- w4''
        #pragma unroll
        for (int k = 0; k < 16; ++k) {
            uint2 e = mb[k * 64 + lane];
            float d = __uint_as_float(e.x);
            if (d < __builtin_inff()) insert16(d, (int)e.y, td, ti);
        }

        // ---- emit features: out[b][q][a][0..16][0..3] as float32 ----
        float4* o = (float4*)(out + (((size_t)(b * Q_N + q) * A_N + a) * 17) * 4);
        o[0] = make_float4(vqx, vqy, vqz, qdist);

        #pragma unroll
        for (int j = 0; j < 16; ++j) {
            float4 wv;
            if (td[j] == __builtin_inff()) {
                wv = make_float4(0.0f, 0.0f, 0.0f, 0.0f);   // padded -> exact zeros
            } else {
                const float* hp = pbase + (size_t)ti[j] * 3;
                float hx = __fsub_rn(hp[0], qx);
                float hy = __fsub_rn(hp[1], qy);
                float hz = __fsub_rn(hp[2], qz);
                float sq = dot3_rn(hx, hy, hz, hx, hy, hz);
                float md = (sq == 0.0f) ? 0.0f : __fsqrt_rn(sq);
                wv = make_float4(hx, hy, hz, md);
            }
            o[1 + j] = wv;
        }
    }
}

extern "C" void kernel_launch(void* const* d_in, const int* in_sizes, int n_in,
                              void* d_out, int out_size, void* d_ws, size_t ws_size,
                              hipStream_t stream) {
    const float* pcd = (const float*)d_in[0];
    const float* qry = (const float*)d_in[1];
    const float* anc = (const float*)d_in[2];
    float* out = (float*)d_out;

    dim3 grid(2 * A_N * 8);   // (b, anchor, 64-query chunk) = 768 blocks
    dim3 block(512);          // 8 waves: each stages+scans a 256-point slice
    hipLaunchKernelGGL(aronet_kernel, grid, block, 0, stream, pcd, qry, anc, out);
}

// Round 16
// 206.123 us; speedup vs baseline: 6.3605x; 2.3319x over previous
//
#include <hip/hip_runtime.h>

#define P_N 2048
#define Q_N 512
#define A_N 48
#define WPTS 512         // points per wave
#define CHUNK 256
#define CAP 24           // u8 candidate slots per thread (chunk-local offsets)
#define LSTR 25          // cand stride in bytes

// plain numpy-f32 3-term dot: ((x*x' + y*y') + z*z'), each op separately rounded
__device__ __forceinline__ float dot3_rn(float ax, float ay, float az,
                                         float bx, float by, float bz) {
    return __fadd_rn(__fadd_rn(__fmul_rn(ax, bx), __fmul_rn(ay, by)),
                     __fmul_rn(az, bz));
}

// XLA fused mul+reduce FMA chain: fma(z,z', fma(y,y', rn(x*x')))
__device__ __forceinline__ float dot3_fma(float ax, float ay, float az,
                                          float bx, float by, float bz) {
    return __fmaf_rn(az, bz, __fmaf_rn(ay, by, __fmul_rn(ax, bx)));
}

// sorted insert (ascending) into 16-entry register list; stable for equal keys
__device__ __forceinline__ void insert16(float d, int idx, float (&td)[16], int (&ti)[16]) {
    if (d >= td[15]) return;
    #pragma unroll
    for (int j = 15; j >= 1; --j) {
        float oldd = td[j]; int oldi = ti[j];
        bool up   = (d < td[j - 1]);
        bool here = (d < oldd);
        td[j] = up ? td[j - 1] : (here ? d : oldd);
        ti[j] = up ? ti[j - 1] : (here ? idx : oldi);
    }
    if (d < td[0]) { ti[0] = idx; td[0] = d; }
}

__global__ __launch_bounds__(256, 4) void aronet_kernel(
        const float* __restrict__ pcd, const float* __restrict__ qry,
        const float* __restrict__ anc, float* __restrict__ out) {
    __shared__ float4 spt[P_N];              // 32 KiB; dead after scan -> merge bufs
    __shared__ unsigned char cand[256 * LSTR];  // 6400 B candidate lists (u8 offsets)

    uint2* mbuf = (uint2*)spt;               // merge overlay: buf w-1 at (w-1)*1024

    const int tid  = threadIdx.x;
    const int lane = tid & 63;
    const int w    = tid >> 6;               // wave 0..3

    const int bid = blockIdx.x;              // (b*48 + a)*8 + qc
    const int qc  = bid & 7;
    const int ba  = bid >> 3;                // 0..95
    const int a   = ba % A_N;
    const int b   = ba / A_N;

    const float ax = anc[(b * A_N + a) * 3 + 0];
    const float ay = anc[(b * A_N + a) * 3 + 1];
    const float az = anc[(b * A_N + a) * 3 + 2];

    // ---- each wave stages ITS OWN point-quarter (verified profile:
    //      d2 plain, dist = sqrt_rn(d2), dir = vec * rn(1/dist)) ----
    const float* pbase = pcd + (size_t)b * P_N * 3;
    const int pq0 = w * WPTS;
    for (int i = lane; i < WPTS; i += 64) {
        const int p = pq0 + i;
        float vx = __fsub_rn(pbase[p * 3 + 0], ax);
        float vy = __fsub_rn(pbase[p * 3 + 1], ay);
        float vz = __fsub_rn(pbase[p * 3 + 2], az);
        float d2 = dot3_rn(vx, vy, vz, vx, vy, vz);
        float dist = __fsqrt_rn(d2);
        float r = __fdiv_rn(1.0f, dist);
        spt[p] = make_float4(dist, __fmul_rn(vx, r), __fmul_rn(vy, r), __fmul_rn(vz, r));
    }

    // ---- per-lane query setup (identical math to passing kernel) ----
    const int q = (qc << 6) + lane;
    const float qx = qry[((size_t)b * Q_N + q) * 3 + 0];
    const float qy = qry[((size_t)b * Q_N + q) * 3 + 1];
    const float qz = qry[((size_t)b * Q_N + q) * 3 + 2];
    const float vqx = __fsub_rn(qx, ax);
    const float vqy = __fsub_rn(qy, ay);
    const float vqz = __fsub_rn(qz, az);
    const float qd2 = dot3_rn(vqx, vqy, vqz, vqx, vqy, vqz);
    const float qdist = __fsqrt_rn(qd2);
    const float qr = __fdiv_rn(1.0f, qdist);
    const float dqx = __fmul_rn(vqx, qr);
    const float dqy = __fmul_rn(vqy, qr);
    const float dqz = __fmul_rn(vqz, qr);

    const float COS_TH = 0.9659258262890683f;

    float td[16]; int ti[16];
    #pragma unroll
    for (int j = 0; j < 16; ++j) { td[j] = __builtin_inff(); ti[j] = 0; }

    // ---- scan own quarter in chunks: compact candidates, flush per chunk ----
    const int lbase = tid * LSTR;
    int cnt = 0;
    for (int c0 = pq0; c0 < pq0 + WPTS; c0 += CHUNK) {
        #pragma unroll 8
        for (int p = c0; p < c0 + CHUNK; ++p) {
            float4 pt = spt[p];                  // wave-uniform broadcast read
            float cosv = dot3_fma(dqx, dqy, dqz, pt.y, pt.z, pt.w);
            if (!(cosv <= COS_TH)) {             // candidate iff !(cos <= TH)
                if (cnt < CAP) { cand[lbase + cnt] = (unsigned char)(p - c0); cnt++; }
                else insert16(pt.x, p, td, ti);  // overflow fallback (P ~ 1e-11)
            }
        }
        for (int k = 0; k < cnt; ++k) {          // ascending order preserved
            int i = c0 + cand[lbase + k];
            insert16(spt[i].x, i, td, ti);
        }
        cnt = 0;
    }

    // ---- serial merge (r11-proven): w1..w3 publish, w0 merges ascending ----
    __syncthreads();                             // B1: all spt reads done, spt dead
    if (w > 0) {
        uint2* mb = mbuf + (w - 1) * 1024;
        #pragma unroll
        for (int k = 0; k < 16; ++k)
            mb[k * 64 + lane] = make_uint2(__float_as_uint(td[k]), (unsigned)ti[k]);
    }
    __syncthreads();                             // B2

    if (w == 0) {
        for (int w2 = 0; w2 < 3; ++w2) {         // ascending wave = ascending index
            const uint2* mb = mbuf + w2 * 1024;
            #pragma unroll
            for (int k = 0; k < 16; ++k) {
                uint2 e = mb[k * 64 + lane];
                float d = __uint_as_float(e.x);
                if (d < __builtin_inff()) insert16(d, (int)e.y, td, ti);
            }
        }

        // ---- emit features: out[b][q][a][0..16][0..3] as float32 ----
        float4* o = (float4*)(out + (((size_t)(b * Q_N + q) * A_N + a) * 17) * 4);
        o[0] = make_float4(vqx, vqy, vqz, qdist);

        #pragma unroll
        for (int j = 0; j < 16; ++j) {
            float4 wv;
            if (td[j] == __builtin_inff()) {
                wv = make_float4(0.0f, 0.0f, 0.0f, 0.0f);   // padded -> exact zeros
            } else {
                const float* hp = pbase + (size_t)ti[j] * 3;
                float hx = __fsub_rn(hp[0], qx);
                float hy = __fsub_rn(hp[1], qy);
                float hz = __fsub_rn(hp[2], qz);
                float sq = dot3_rn(hx, hy, hz, hx, hy, hz);
                float md = (sq == 0.0f) ? 0.0f : __fsqrt_rn(sq);
                wv = make_float4(hx, hy, hz, md);
            }
            o[1 + j] = wv;
        }
    }
}

extern "C" void kernel_launch(void* const* d_in, const int* in_sizes, int n_in,
                              void* d_out, int out_size, void* d_ws, size_t ws_size,
                              hipStream_t stream) {
    const float* pcd = (const float*)d_in[0];
    const float* qry = (const float*)d_in[1];
    const float* anc = (const float*)d_in[2];
    float* out = (float*)d_out;

    dim3 grid(2 * A_N * 8);   // (b, anchor, 64-query chunk) = 768 blocks
    dim3 block(256);          // 4 waves: each stages+scans a point-quarter
    hipLaunchKernelGGL(aronet_kernel, grid, block, 0, stream, pcd, qry, anc, out);
}